// Round 6
// baseline (759.143 us; speedup 1.0000x reference)
//
#include <hip/hip_runtime.h>

// Problem constants
#define B_   4
#define SQS  2048
#define SKS  2048
#define DM   1024
#define H_   16
#define MT   8192      // B_*SQS tokens

typedef __attribute__((ext_vector_type(8))) short bf16x8;
typedef __attribute__((ext_vector_type(4))) float f32x4;

__device__ __forceinline__ float bf2f(unsigned int u) { return __uint_as_float(u << 16); }
__device__ __forceinline__ unsigned short f2bf(float f) {
  unsigned int u = __float_as_uint(f);
  return (unsigned short)((u + 0x7fffu + ((u >> 16) & 1u)) >> 16);
}
// pack two floats -> two bf16 (round-half-up): [hi16(b) : hi16(a)]
__device__ __forceinline__ unsigned int pk_bf16(float a, float b) {
  return __builtin_amdgcn_perm(__float_as_uint(b) + 0x8000u,
                               __float_as_uint(a) + 0x8000u, 0x07060302u);
}
// truncating pack (rounding bias pre-compensated in mask bias)
__device__ __forceinline__ unsigned int pk_trunc(float a, float b) {
  return __builtin_amdgcn_perm(__float_as_uint(b), __float_as_uint(a), 0x07060302u);
}
__device__ __forceinline__ float fexp2(float x) {
#if __has_builtin(__builtin_amdgcn_exp2f)
  return __builtin_amdgcn_exp2f(x);
#else
  return __expf(x * 0.69314718056f);
#endif
}
__device__ __forceinline__ void async16(const void* g, void* l) {
  __builtin_amdgcn_global_load_lds((const __attribute__((address_space(1))) unsigned int*)g,
                                   (__attribute__((address_space(3))) unsigned int*)l,
                                   16, 0, 0);
}

// 1/sqrt(D) * log2(e): folded into K projection epilogue
#define KSCALE 0.0450842200f
// log2(1 + 2^-9): compensates truncating bf16 pack of P (cancels in l-normalization)
#define BIAS_UNMASKED 0.0028151213f

// ---------------------------------------------------------------------------
// Merged prep: [0,24576) fp32->bf16 cvt of q/k/v ; [24576,28672) W transpose ;
// [28672,28704) mask bias.
// ---------------------------------------------------------------------------
__global__ __launch_bounds__(256)
void prep_all(const float* __restrict__ q, const float* __restrict__ k,
              const float* __restrict__ v, const int* __restrict__ mask,
              const float* __restrict__ Wq, const float* __restrict__ Wk,
              const float* __restrict__ Wv, const float* __restrict__ Wo,
              unsigned short* __restrict__ qi, unsigned short* __restrict__ ki,
              unsigned short* __restrict__ vi,
              unsigned short* __restrict__ Wqt, unsigned short* __restrict__ Wkt,
              unsigned short* __restrict__ Wvt, unsigned short* __restrict__ Wot,
              float* __restrict__ mskb)
{
  __shared__ float s[32][33];
  const int bx = blockIdx.x, tid = threadIdx.x;
  if (bx < 24576) {
    const int which = bx >> 13, i = bx & 8191;
    const float* src = (which == 0) ? q : (which == 1) ? k : v;
    unsigned short* dst = (which == 0) ? qi : (which == 1) ? ki : vi;
    size_t o = ((size_t)i * 256 + tid) * 4;
    float4 f = *(const float4*)(src + o);
    uint2 u;
    u.x = pk_bf16(f.x, f.y);
    u.y = pk_bf16(f.z, f.w);
    *(uint2*)(dst + o) = u;
  } else if (bx < 28672) {
    const int idx = bx - 24576;
    const int w = idx >> 10, t = idx & 1023;
    const int n0 = (t & 31) * 32, k0 = (t >> 5) * 32;
    const float* W = (w == 0) ? Wq : (w == 1) ? Wk : (w == 2) ? Wv : Wo;
    unsigned short* Wt = (w == 0) ? Wqt : (w == 1) ? Wkt : (w == 2) ? Wvt : Wot;
#pragma unroll
    for (int p = 0; p < 4; p++) {
      int c = p * 256 + tid;
      int r = c >> 5, cc = c & 31;
      s[r][cc] = W[(size_t)(k0 + r) * DM + n0 + cc];
    }
    __syncthreads();
#pragma unroll
    for (int p = 0; p < 4; p++) {
      int c = p * 256 + tid;
      int r = c >> 5, cc = c & 31;
      Wt[(size_t)(n0 + r) * DM + k0 + cc] = f2bf(s[cc][r]);
    }
  } else {
    int i = (bx - 28672) * 256 + tid;
    mskb[i] = mask[i] ? BIAS_UNMASKED : -1e30f;
  }
}

// ---------------------------------------------------------------------------
// Fused QKV GEMM, BK=64, XOR-swizzled staging, XCD-aware remap.
// z==1 (K) pre-scaled by KSCALE. z==2 (V) written directly in vT layout
// (transposed + per-64 key permutation pi(k) = (i&1)*32 + qd*8 + (i>>1)*4 + r).
// ---------------------------------------------------------------------------
__global__ __launch_bounds__(256)
void qkv_gemm(const unsigned short* __restrict__ A0, const unsigned short* __restrict__ A1,
              const unsigned short* __restrict__ A2,
              const unsigned short* __restrict__ W0, const unsigned short* __restrict__ W1,
              const unsigned short* __restrict__ W2,
              const float* __restrict__ s0, const float* __restrict__ s1,
              const float* __restrict__ s2,
              unsigned short* __restrict__ o0, unsigned short* __restrict__ o1,
              unsigned short* __restrict__ vT)
{
  // grid = 1536 linear blocks; L%8 = XCD; per XCD: 24 (m,z)-tiles x 8 n-blocks
  const int L = blockIdx.x + (blockIdx.y << 3) + (blockIdx.z << 9);
  const int g = L & 7, i5 = L >> 3;
  const int nblk = i5 & 7;
  const int yz = (i5 >> 3) + g * 24;     // [0,192)
  const int mblk = yz & 63;
  const int z = yz >> 6;

  const unsigned short* A  = (z == 0) ? A0 : (z == 1) ? A1 : A2;
  const unsigned short* Wt = (z == 0) ? W0 : (z == 1) ? W1 : W2;
  const float* bias        = (z == 0) ? s0 : (z == 1) ? s1 : s2;

  __shared__ short As[128 * 64];
  __shared__ short Bs[128 * 64];
  const int tid = threadIdx.x;
  const int m0 = mblk * 128, n0 = nblk * 128;
  const int wave = tid >> 6, ln = tid & 15, qd = (tid & 63) >> 4;
  const int wm = (wave >> 1) * 64, wn = (wave & 1) * 64;

  int srow[4], sgj[4];
#pragma unroll
  for (int u = 0; u < 4; u++) {
    int c = u * 256 + tid;
    srow[u] = c >> 3;
    sgj[u] = ((c & 7) ^ (srow[u] & 7)) * 8;
  }

  f32x4 acc[4][4];
  const f32x4 vzero = {0.f, 0.f, 0.f, 0.f};
#pragma unroll
  for (int i = 0; i < 4; i++)
#pragma unroll
    for (int j = 0; j < 4; j++) acc[i][j] = vzero;

  for (int k0 = 0; k0 < DM; k0 += 64) {
    __syncthreads();
#pragma unroll
    for (int u = 0; u < 4; u++) {
      int c = u * 256 + tid;
      async16(A  + (size_t)(m0 + srow[u]) * DM + k0 + sgj[u], (char*)As + c * 16);
      async16(Wt + (size_t)(n0 + srow[u]) * DM + k0 + sgj[u], (char*)Bs + c * 16);
    }
    __syncthreads();

#pragma unroll
    for (int kk = 0; kk < 2; kk++) {
      const int ch = ((kk * 4 + qd) ^ (ln & 7)) * 8;
      bf16x8 af[4], bfr[4];
#pragma unroll
      for (int i = 0; i < 4; i++)
        af[i] = *(const bf16x8*)(As + (wm + i * 16 + ln) * 64 + ch);
#pragma unroll
      for (int j = 0; j < 4; j++)
        bfr[j] = *(const bf16x8*)(Bs + (wn + j * 16 + ln) * 64 + ch);
#pragma unroll
      for (int i = 0; i < 4; i++)
#pragma unroll
        for (int j = 0; j < 4; j++)
          acc[i][j] = __builtin_amdgcn_mfma_f32_16x16x32_bf16(af[i], bfr[j], acc[i][j], 0, 0, 0);
    }
  }

  if (z != 2) {
    unsigned short* C = (z == 0) ? o0 : o1;
    const float sc = (z == 1) ? KSCALE : 1.0f;
#pragma unroll
    for (int j = 0; j < 4; j++) {
      int col = n0 + wn + j * 16 + ln;
      float bj = bias[col];
#pragma unroll
      for (int i = 0; i < 4; i++) {
        int row = m0 + wm + i * 16 + qd * 4;
#pragma unroll
        for (int r = 0; r < 4; r++)
          C[(size_t)(row + r) * DM + col] = f2bf((acc[i][j][r] + bj) * sc);
      }
    }
  } else {
    // direct vT write: vT[(b*H+h)*64+d][SK] with per-64 key permutation
#pragma unroll
    for (int j = 0; j < 4; j++) {
      int col = n0 + wn + j * 16 + ln;
      int h = col >> 6, d = col & 63;
      float bj = bias[col];
#pragma unroll
      for (int i = 0; i < 4; i++) {
        int tok0 = m0 + wm + i * 16 + qd * 4;
        int bb = tok0 >> 11;
        int kcol = ((tok0 & 2047) & ~63) + (i & 1) * 32 + qd * 8 + ((i >> 1) & 1) * 4;
        uint2 u;
        u.x = pk_bf16(acc[i][j][0] + bj, acc[i][j][1] + bj);
        u.y = pk_bf16(acc[i][j][2] + bj, acc[i][j][3] + bj);
        *(uint2*)(vT + ((size_t)(bb * H_ + h) * 64 + d) * SKS + kcol) = u;
      }
    }
  }
}

// ---------------------------------------------------------------------------
// Single GEMM (Wo, ReLU option), BK=64 swizzled, XCD-aware remap
// ---------------------------------------------------------------------------
__global__ __launch_bounds__(256)
void gemm_bf16(const unsigned short* __restrict__ A,
               const unsigned short* __restrict__ Wt,
               const float* __restrict__ bias,
               unsigned short* __restrict__ C,
               int relu)
{
  const int L = blockIdx.x + (blockIdx.y << 3);
  const int g = L & 7, i5 = L >> 3;
  const int nblk = i5 & 7;
  const int mblk = (i5 >> 3) + (g << 3);

  __shared__ short As[128 * 64];
  __shared__ short Bs[128 * 64];
  const int tid = threadIdx.x;
  const int m0 = mblk * 128, n0 = nblk * 128;
  const int wave = tid >> 6, ln = tid & 15, qd = (tid & 63) >> 4;
  const int wm = (wave >> 1) * 64, wn = (wave & 1) * 64;

  int srow[4], sgj[4];
#pragma unroll
  for (int u = 0; u < 4; u++) {
    int c = u * 256 + tid;
    srow[u] = c >> 3;
    sgj[u] = ((c & 7) ^ (srow[u] & 7)) * 8;
  }

  f32x4 acc[4][4];
  const f32x4 vzero = {0.f, 0.f, 0.f, 0.f};
#pragma unroll
  for (int i = 0; i < 4; i++)
#pragma unroll
    for (int j = 0; j < 4; j++) acc[i][j] = vzero;

  for (int k0 = 0; k0 < DM; k0 += 64) {
    __syncthreads();
#pragma unroll
    for (int u = 0; u < 4; u++) {
      int c = u * 256 + tid;
      async16(A  + (size_t)(m0 + srow[u]) * DM + k0 + sgj[u], (char*)As + c * 16);
      async16(Wt + (size_t)(n0 + srow[u]) * DM + k0 + sgj[u], (char*)Bs + c * 16);
    }
    __syncthreads();

#pragma unroll
    for (int kk = 0; kk < 2; kk++) {
      const int ch = ((kk * 4 + qd) ^ (ln & 7)) * 8;
      bf16x8 af[4], bfr[4];
#pragma unroll
      for (int i = 0; i < 4; i++)
        af[i] = *(const bf16x8*)(As + (wm + i * 16 + ln) * 64 + ch);
#pragma unroll
      for (int j = 0; j < 4; j++)
        bfr[j] = *(const bf16x8*)(Bs + (wn + j * 16 + ln) * 64 + ch);
#pragma unroll
      for (int i = 0; i < 4; i++)
#pragma unroll
        for (int j = 0; j < 4; j++)
          acc[i][j] = __builtin_amdgcn_mfma_f32_16x16x32_bf16(af[i], bfr[j], acc[i][j], 0, 0, 0);
    }
  }

#pragma unroll
  for (int j = 0; j < 4; j++) {
    int col = n0 + wn + j * 16 + ln;
    float bj = bias[col];
#pragma unroll
    for (int i = 0; i < 4; i++) {
      int row = m0 + wm + i * 16 + qd * 4;
#pragma unroll
      for (int r = 0; r < 4; r++) {
        float v = acc[i][j][r] + bj;
        if (relu) v = fmaxf(v, 0.f);
        C[(size_t)(row + r) * DM + col] = f2bf(v);
      }
    }
  }
}

// ---------------------------------------------------------------------------
// Flash attention fwd, K-split=2. Block = 256 q x 1024 keys (8 k-tiles of 128).
// grid 1024 -> 4 blocks/CU, 4 waves/SIMD (latency hiding). Writes UNNORMALIZED
// O-half (bf16) + l (fp32); merge is fused into the first LayerNorm.
// ---------------------------------------------------------------------------
__global__ __launch_bounds__(256, 4)
void attn_fwd(const unsigned short* __restrict__ qp,
              const unsigned short* __restrict__ kp,
              const unsigned short* __restrict__ vT,
              const float* __restrict__ maskb,
              unsigned short* __restrict__ O0,   // [MT][DM] unnormalized, half 0
              unsigned short* __restrict__ O1,   // half 1
              float* __restrict__ lws)           // [2][(b*H+h)*SQS + q]
{
  __shared__ short Ks[128 * 64];    // [key][d],  swizzled 16B chunks
  __shared__ short Vs[64 * 128];    // [d][k'],   swizzled 16B chunks
  __shared__ float bias_s[128];

  const int tid = threadIdx.x;
  // grid = 1024 linear; L%8 = XCD; per XCD: 8 bh x (8 qblk x 2 half)
  const int L = blockIdx.x + (blockIdx.y << 4) + (blockIdx.z << 8);
  const int g = L & 7, i5 = L >> 3;
  const int half = i5 & 1;
  const int qblk = (i5 >> 1) & 7;
  const int bh = (i5 >> 4) + (g << 3);   // [0,64)
  const int h = bh & 15, b = bh >> 4;
  const int q0 = qblk * 256;
  const int koff0 = half * (SKS / 2);
  const int wave = tid >> 6, ln = tid & 15, qd = (tid & 63) >> 4;

  int kRow[4], kOff[4], vRow[4], vOff[4];
#pragma unroll
  for (int u = 0; u < 4; u++) {
    int c = u * 256 + tid;
    kRow[u] = c >> 3;
    kOff[u] = ((c & 7) ^ (kRow[u] & 7)) * 8;
    vRow[u] = c >> 4;
    int j = c & 15;
    vOff[u] = ((j & 8) | ((j ^ vRow[u]) & 7)) * 8;
  }

  const unsigned short* kbase = kp + (size_t)(b * SKS) * DM + (h << 6);
  const unsigned short* vbase = vT + (size_t)((b * H_ + h) * 64) * SKS;

  // Q fragments: 4 q-groups x 2 d-halves (B-operand layout), once per block
  bf16x8 qf[4][2];
#pragma unroll
  for (int gq = 0; gq < 4; gq++) {
    const unsigned short* qrow =
        qp + (size_t)(b * SQS + q0 + wave * 64 + gq * 16 + ln) * DM + (h << 6);
    qf[gq][0] = *(const bf16x8*)(qrow + qd * 8);
    qf[gq][1] = *(const bf16x8*)(qrow + 32 + qd * 8);
  }

  union { bf16x8 v; unsigned int u[4]; } onesf;
  onesf.u[0] = onesf.u[1] = onesf.u[2] = onesf.u[3] = 0x3F803F80u;

  const f32x4 vzero = {0.f, 0.f, 0.f, 0.f};
  f32x4 oA[4][4], lacc[4];
#pragma unroll
  for (int gq = 0; gq < 4; gq++) {
    lacc[gq] = vzero;
#pragma unroll
    for (int t = 0; t < 4; t++) oA[gq][t] = vzero;
  }

  for (int kt = 0; kt < SKS / 2 / 128; kt++) {
    const int k0 = koff0 + kt * 128;
    __syncthreads();
    if (tid < 128) bias_s[tid] = maskb[b * SKS + k0 + tid];
#pragma unroll
    for (int u = 0; u < 4; u++) {
      int c = u * 256 + tid;
      async16(kbase + (size_t)(k0 + kRow[u]) * DM + kOff[u], (char*)Ks + c * 16);
      async16(vbase + (size_t)vRow[u] * SKS + k0 + vOff[u], (char*)Vs + c * 16);
    }
    __syncthreads();

#pragma unroll
    for (int h2 = 0; h2 < 2; h2++) {
      // hoisted K fragments + bias (shared by all 4 q-groups)
      bf16x8 kf[4][2];
      f32x4 btv[4];
#pragma unroll
      for (int t = 0; t < 4; t++) {
        const short* krow = Ks + (h2 * 64 + t * 16 + ln) * 64;
        kf[t][0] = *(const bf16x8*)(krow + ((0 + qd) ^ (ln & 7)) * 8);
        kf[t][1] = *(const bf16x8*)(krow + ((4 + qd) ^ (ln & 7)) * 8);
        btv[t] = *(const f32x4*)(bias_s + h2 * 64 + t * 16 + qd * 4);
      }

      bf16x8 pf[4][2];
#pragma unroll
      for (int gq = 0; gq < 4; gq++) {
        f32x4 sS[4];
#pragma unroll
        for (int t = 0; t < 4; t++) {
          f32x4 a = __builtin_amdgcn_mfma_f32_16x16x32_bf16(kf[t][0], qf[gq][0], btv[t], 0, 0, 0);
          sS[t]   = __builtin_amdgcn_mfma_f32_16x16x32_bf16(kf[t][1], qf[gq][1], a,      0, 0, 0);
        }
        float p[4][4];
#pragma unroll
        for (int t = 0; t < 4; t++) {
          p[t][0] = fexp2(sS[t][0]);
          p[t][1] = fexp2(sS[t][1]);
          p[t][2] = fexp2(sS[t][2]);
          p[t][3] = fexp2(sS[t][3]);
        }
        union { bf16x8 v; unsigned int u[4]; } P0, P1;
        P0.u[0] = pk_trunc(p[0][0], p[0][1]);
        P0.u[1] = pk_trunc(p[0][2], p[0][3]);
        P0.u[2] = pk_trunc(p[2][0], p[2][1]);
        P0.u[3] = pk_trunc(p[2][2], p[2][3]);
        P1.u[0] = pk_trunc(p[1][0], p[1][1]);
        P1.u[1] = pk_trunc(p[1][2], p[1][3]);
        P1.u[2] = pk_trunc(p[3][0], p[3][1]);
        P1.u[3] = pk_trunc(p[3][2], p[3][3]);
        pf[gq][0] = P0.v;
        pf[gq][1] = P1.v;
        lacc[gq] = __builtin_amdgcn_mfma_f32_16x16x32_bf16(pf[gq][0], onesf.v, lacc[gq], 0, 0, 0);
        lacc[gq] = __builtin_amdgcn_mfma_f32_16x16x32_bf16(pf[gq][1], onesf.v, lacc[gq], 0, 0, 0);
      }

      // ---- O += P V, V fragments shared across the 4 q-groups ----
#pragma unroll
      for (int t2 = 0; t2 < 4; t2++) {
        const short* vrow = Vs + (t2 * 16 + ln) * 128;
        bf16x8 vf0 = *(const bf16x8*)(vrow + (h2 * 8 + ((0 + qd) ^ (ln & 7))) * 8);
        bf16x8 vf1 = *(const bf16x8*)(vrow + (h2 * 8 + ((4 + qd) ^ (ln & 7))) * 8);
#pragma unroll
        for (int gq = 0; gq < 4; gq++) {
          oA[gq][t2] = __builtin_amdgcn_mfma_f32_16x16x32_bf16(pf[gq][0], vf0, oA[gq][t2], 0, 0, 0);
          oA[gq][t2] = __builtin_amdgcn_mfma_f32_16x16x32_bf16(pf[gq][1], vf1, oA[gq][t2], 0, 0, 0);
        }
      }
    }
  }

  // ---- epilogue: store UNNORMALIZED O-half + l ----
  unsigned short* obuf = half ? O1 : O0;
  float* lbuf = lws + (size_t)half * (B_ * H_ * SQS);
#pragma unroll
  for (int gq = 0; gq < 4; gq++) {
    int qloc = q0 + wave * 64 + gq * 16 + qd * 4;
    if (ln == 0) {
#pragma unroll
      for (int r = 0; r < 4; r++)
        lbuf[(size_t)(b * H_ + h) * SQS + qloc + r] = lacc[gq][r];
    }
#pragma unroll
    for (int t2 = 0; t2 < 4; t2++)
#pragma unroll
      for (int r = 0; r < 4; r++) {
        size_t idx = (size_t)(b * SQS + qloc + r) * DM + (h << 6) + t2 * 16 + ln;
        obuf[idx] = f2bf(oA[gq][t2][r]);
      }
  }
}

// ---------------------------------------------------------------------------
// LayerNorm(qp + (O0+O1)/(l0+l1)) * g + b -> bf16 (fused K-split merge + LN1)
// ---------------------------------------------------------------------------
__global__ __launch_bounds__(256)
void ln_merge(const unsigned short* __restrict__ Xa, const unsigned short* __restrict__ O0,
              const unsigned short* __restrict__ O1, const float* __restrict__ lws,
              const float* __restrict__ gamma, const float* __restrict__ beta,
              unsigned short* __restrict__ outb)
{
  const int row = blockIdx.x, tid = threadIdx.x;
  const int b = row >> 11, q = row & 2047;
  const int h = tid >> 4;
  const size_t lidx = (size_t)(b * H_ + h) * SQS + q;
  float la = lws[lidx], lb2 = lws[lidx + (size_t)(B_ * H_ * SQS)];
  float lsum = la + lb2;
  float linv = (lsum > 0.f) ? 1.0f / lsum : 0.f;

  const size_t base = (size_t)row * DM + tid * 4;
  uint2 ua = *(const uint2*)(Xa + base);
  uint2 u0 = *(const uint2*)(O0 + base);
  uint2 u1 = *(const uint2*)(O1 + base);
  float v0 = bf2f(ua.x & 0xffffu) + (bf2f(u0.x & 0xffffu) + bf2f(u1.x & 0xffffu)) * linv;
  float v1 = bf2f(ua.x >> 16)     + (bf2f(u0.x >> 16)     + bf2f(u1.x >> 16))     * linv;
  float v2 = bf2f(ua.y & 0xffffu) + (bf2f(u0.y & 0xffffu) + bf2f(u1.y & 0xffffu)) * linv;
  float v3 = bf2f(ua.y >> 16)     + (bf2f(u0.y >> 16)     + bf2f(u1.y >> 16))     * linv;

  float s  = (v0 + v1) + (v2 + v3);
  float s2 = (v0 * v0 + v1 * v1) + (v2 * v2 + v3 * v3);
#pragma unroll
  for (int off = 1; off < 64; off <<= 1) {
    s  += __shfl_xor(s, off);
    s2 += __shfl_xor(s2, off);
  }
  __shared__ float red[8];
  if ((tid & 63) == 0) { red[tid >> 6] = s; red[4 + (tid >> 6)] = s2; }
  __syncthreads();
  float S  = (red[0] + red[1]) + (red[2] + red[3]);
  float S2 = (red[4] + red[5]) + (red[6] + red[7]);
  float mean = S * (1.0f / 1024.0f);
  float var  = S2 * (1.0f / 1024.0f) - mean * mean;
  float rstd = rsqrtf(var + 1e-6f);
  int c = tid * 4;
  float o0 = (v0 - mean) * rstd * gamma[c + 0] + beta[c + 0];
  float o1 = (v1 - mean) * rstd * gamma[c + 1] + beta[c + 1];
  float o2 = (v2 - mean) * rstd * gamma[c + 2] + beta[c + 2];
  float o3 = (v3 - mean) * rstd * gamma[c + 3] + beta[c + 3];
  uint2 o;
  o.x = pk_bf16(o0, o1);
  o.y = pk_bf16(o2, o3);
  *(uint2*)(outb + base) = o;
}

// ---------------------------------------------------------------------------
// LayerNorm(Xa + Xb) * g + b -> fp32 (final LN)
// ---------------------------------------------------------------------------
__global__ __launch_bounds__(256)
void ln_fuse(const unsigned short* __restrict__ Xa, const unsigned short* __restrict__ Xb,
             const float* __restrict__ gamma, const float* __restrict__ beta,
             float* __restrict__ outf)
{
  const int row = blockIdx.x, tid = threadIdx.x;
  const size_t base = (size_t)row * DM + tid * 4;
  uint2 ua = *(const uint2*)(Xa + base);
  uint2 ub = *(const uint2*)(Xb + base);
  float v0 = bf2f(ua.x & 0xffffu) + bf2f(ub.x & 0xffffu);
  float v1 = bf2f(ua.x >> 16)     + bf2f(ub.x >> 16);
  float v2 = bf2f(ua.y & 0xffffu) + bf2f(ub.y & 0xffffu);
  float v3 = bf2f(ua.y >> 16)     + bf2f(ub.y >> 16);
  float s  = (v0 + v1) + (v2 + v3);
  float s2 = (v0 * v0 + v1 * v1) + (v2 * v2 + v3 * v3);
#pragma unroll
  for (int off = 1; off < 64; off <<= 1) {
    s  += __shfl_xor(s, off);
    s2 += __shfl_xor(s2, off);
  }
  __shared__ float red[8];
  if ((tid & 63) == 0) { red[tid >> 6] = s; red[4 + (tid >> 6)] = s2; }
  __syncthreads();
  float S  = (red[0] + red[1]) + (red[2] + red[3]);
  float S2 = (red[4] + red[5]) + (red[6] + red[7]);
  float mean = S * (1.0f / 1024.0f);
  float var  = S2 * (1.0f / 1024.0f) - mean * mean;
  float rstd = rsqrtf(var + 1e-6f);
  int c = tid * 4;
  float o0 = (v0 - mean) * rstd * gamma[c + 0] + beta[c + 0];
  float o1 = (v1 - mean) * rstd * gamma[c + 1] + beta[c + 1];
  float o2 = (v2 - mean) * rstd * gamma[c + 2] + beta[c + 2];
  float o3 = (v3 - mean) * rstd * gamma[c + 3] + beta[c + 3];
  float4 o = {o0, o1, o2, o3};
  *(float4*)(outf + base) = o;
}

// ---------------------------------------------------------------------------
extern "C" void kernel_launch(void* const* d_in, const int* in_sizes, int n_in,
                              void* d_out, int out_size, void* d_ws, size_t ws_size,
                              hipStream_t stream)
{
  (void)in_sizes; (void)n_in; (void)out_size; (void)ws_size;
  const float* q    = (const float*)d_in[0];
  const float* k    = (const float*)d_in[1];
  const float* v    = (const float*)d_in[2];
  const int*   mask = (const int*)  d_in[3];
  const float* Wq   = (const float*)d_in[4];
  const float* bq   = (const float*)d_in[5];
  const float* Wk   = (const float*)d_in[6];
  const float* bk   = (const float*)d_in[7];
  const float* Wv   = (const float*)d_in[8];
  const float* bv   = (const float*)d_in[9];
  const float* Wo   = (const float*)d_in[10];
  const float* bo   = (const float*)d_in[11];
  const float* g1   = (const float*)d_in[12];
  const float* b1   = (const float*)d_in[13];
  const float* g2   = (const float*)d_in[14];
  const float* b2   = (const float*)d_in[15];

  char* ws = (char*)d_ws;
  const size_t SZ16 = (size_t)16 << 20;
  unsigned short* qi   = (unsigned short*)(ws + 0 * SZ16);
  unsigned short* ki   = (unsigned short*)(ws + 1 * SZ16);
  unsigned short* vi   = (unsigned short*)(ws + 2 * SZ16);
  unsigned short* qpb  = (unsigned short*)(ws + 3 * SZ16);
  unsigned short* kpb  = (unsigned short*)(ws + 4 * SZ16);
  unsigned short* vTb  = (unsigned short*)(ws + 6 * SZ16);
  unsigned short* Wqt  = (unsigned short*)(ws + 7 * SZ16 + ((size_t)0 << 20));
  unsigned short* Wkt  = (unsigned short*)(ws + 7 * SZ16 + ((size_t)2 << 20));
  unsigned short* Wvt  = (unsigned short*)(ws + 7 * SZ16 + ((size_t)4 << 20));
  unsigned short* Wot  = (unsigned short*)(ws + 7 * SZ16 + ((size_t)6 << 20));
  float*          mskb = (float*)         (ws + 7 * SZ16 + ((size_t)8 << 20));
  float*          lws  = (float*)         (ws + 7 * SZ16 + ((size_t)9 << 20));  // 2x512KB
  // dead-buffer reuse:
  unsigned short* O0b  = qi;    // free after qkv
  unsigned short* O1b  = vi;    // free after qkv
  unsigned short* xb   = ki;    // free after qkv
  unsigned short* hb   = vTb;   // free after attn

  prep_all     <<<28704,            256, 0, stream>>>(q, k, v, mask, Wq, Wk, Wv, Wo,
                                                      qi, ki, vi, Wqt, Wkt, Wvt, Wot, mskb);

  qkv_gemm     <<<dim3(8, 64, 3),   256, 0, stream>>>(qi, ki, vi, Wqt, Wkt, Wvt,
                                                      bq, bk, bv, qpb, kpb, vTb);

  attn_fwd     <<<dim3(16, 16, 4),  256, 0, stream>>>(qpb, kpb, vTb, mskb, O0b, O1b, lws);

  ln_merge     <<<8192,             256, 0, stream>>>(qpb, O0b, O1b, lws, g1, b1, xb);
  gemm_bf16    <<<dim3(8, 64),      256, 0, stream>>>(xb, Wot, bo, hb, 1);
  ln_fuse      <<<8192,             256, 0, stream>>>(xb, hb, g2, b2, (float*)d_out);
}

// Round 7
// 347.036 us; speedup vs baseline: 2.1875x; 2.1875x over previous
//
#include <hip/hip_runtime.h>

// Problem constants
#define B_   4
#define SQS  2048
#define SKS  2048
#define DM   1024
#define H_   16
#define MT   8192      // B_*SQS tokens

typedef __attribute__((ext_vector_type(8))) short bf16x8;
typedef __attribute__((ext_vector_type(4))) float f32x4;

__device__ __forceinline__ float bf2f(unsigned int u) { return __uint_as_float(u << 16); }
__device__ __forceinline__ unsigned short f2bf(float f) {
  unsigned int u = __float_as_uint(f);
  return (unsigned short)((u + 0x7fffu + ((u >> 16) & 1u)) >> 16);
}
// pack two floats -> two bf16 (round-half-up): [hi16(b) : hi16(a)]
__device__ __forceinline__ unsigned int pk_bf16(float a, float b) {
  return __builtin_amdgcn_perm(__float_as_uint(b) + 0x8000u,
                               __float_as_uint(a) + 0x8000u, 0x07060302u);
}
// truncating pack (rounding bias pre-compensated in mask bias)
__device__ __forceinline__ unsigned int pk_trunc(float a, float b) {
  return __builtin_amdgcn_perm(__float_as_uint(b), __float_as_uint(a), 0x07060302u);
}
__device__ __forceinline__ float fexp2(float x) {
#if __has_builtin(__builtin_amdgcn_exp2f)
  return __builtin_amdgcn_exp2f(x);
#else
  return __expf(x * 0.69314718056f);
#endif
}
__device__ __forceinline__ void async16(const void* g, void* l) {
  __builtin_amdgcn_global_load_lds((const __attribute__((address_space(1))) unsigned int*)g,
                                   (__attribute__((address_space(3))) unsigned int*)l,
                                   16, 0, 0);
}

// 1/sqrt(D) * log2(e): folded into K projection epilogue
#define KSCALE 0.0450842200f
// log2(1 + 2^-9): compensates truncating bf16 pack of P (cancels in l-normalization)
#define BIAS_UNMASKED 0.0028151213f

// ---------------------------------------------------------------------------
// Merged prep: [0,24576) fp32->bf16 cvt of q/k/v ; [24576,28672) W transpose ;
// [28672,28704) mask bias.
// ---------------------------------------------------------------------------
__global__ __launch_bounds__(256)
void prep_all(const float* __restrict__ q, const float* __restrict__ k,
              const float* __restrict__ v, const int* __restrict__ mask,
              const float* __restrict__ Wq, const float* __restrict__ Wk,
              const float* __restrict__ Wv, const float* __restrict__ Wo,
              unsigned short* __restrict__ qi, unsigned short* __restrict__ ki,
              unsigned short* __restrict__ vi,
              unsigned short* __restrict__ Wqt, unsigned short* __restrict__ Wkt,
              unsigned short* __restrict__ Wvt, unsigned short* __restrict__ Wot,
              float* __restrict__ mskb)
{
  __shared__ float s[32][33];
  const int bx = blockIdx.x, tid = threadIdx.x;
  if (bx < 24576) {
    const int which = bx >> 13, i = bx & 8191;
    const float* src = (which == 0) ? q : (which == 1) ? k : v;
    unsigned short* dst = (which == 0) ? qi : (which == 1) ? ki : vi;
    size_t o = ((size_t)i * 256 + tid) * 4;
    float4 f = *(const float4*)(src + o);
    uint2 u;
    u.x = pk_bf16(f.x, f.y);
    u.y = pk_bf16(f.z, f.w);
    *(uint2*)(dst + o) = u;
  } else if (bx < 28672) {
    const int idx = bx - 24576;
    const int w = idx >> 10, t = idx & 1023;
    const int n0 = (t & 31) * 32, k0 = (t >> 5) * 32;
    const float* W = (w == 0) ? Wq : (w == 1) ? Wk : (w == 2) ? Wv : Wo;
    unsigned short* Wt = (w == 0) ? Wqt : (w == 1) ? Wkt : (w == 2) ? Wvt : Wot;
#pragma unroll
    for (int p = 0; p < 4; p++) {
      int c = p * 256 + tid;
      int r = c >> 5, cc = c & 31;
      s[r][cc] = W[(size_t)(k0 + r) * DM + n0 + cc];
    }
    __syncthreads();
#pragma unroll
    for (int p = 0; p < 4; p++) {
      int c = p * 256 + tid;
      int r = c >> 5, cc = c & 31;
      Wt[(size_t)(n0 + r) * DM + k0 + cc] = f2bf(s[cc][r]);
    }
  } else {
    int i = (bx - 28672) * 256 + tid;
    mskb[i] = mask[i] ? BIAS_UNMASKED : -1e30f;
  }
}

// ---------------------------------------------------------------------------
// Fused QKV GEMM, BK=64, XOR-swizzled staging, XCD-aware remap.
// z==1 (K) pre-scaled by KSCALE. z==2 (V) written directly in vT layout
// (transposed + per-64 key permutation pi(k) = (i&1)*32 + qd*8 + (i>>1)*4 + r).
// ---------------------------------------------------------------------------
__global__ __launch_bounds__(256)
void qkv_gemm(const unsigned short* __restrict__ A0, const unsigned short* __restrict__ A1,
              const unsigned short* __restrict__ A2,
              const unsigned short* __restrict__ W0, const unsigned short* __restrict__ W1,
              const unsigned short* __restrict__ W2,
              const float* __restrict__ s0, const float* __restrict__ s1,
              const float* __restrict__ s2,
              unsigned short* __restrict__ o0, unsigned short* __restrict__ o1,
              unsigned short* __restrict__ vT)
{
  // grid = 1536 linear blocks; L%8 = XCD; per XCD: 24 (m,z)-tiles x 8 n-blocks
  const int L = blockIdx.x + (blockIdx.y << 3) + (blockIdx.z << 9);
  const int g = L & 7, i5 = L >> 3;
  const int nblk = i5 & 7;
  const int yz = (i5 >> 3) + g * 24;     // [0,192)
  const int mblk = yz & 63;
  const int z = yz >> 6;

  const unsigned short* A  = (z == 0) ? A0 : (z == 1) ? A1 : A2;
  const unsigned short* Wt = (z == 0) ? W0 : (z == 1) ? W1 : W2;
  const float* bias        = (z == 0) ? s0 : (z == 1) ? s1 : s2;

  __shared__ short As[128 * 64];
  __shared__ short Bs[128 * 64];
  const int tid = threadIdx.x;
  const int m0 = mblk * 128, n0 = nblk * 128;
  const int wave = tid >> 6, ln = tid & 15, qd = (tid & 63) >> 4;
  const int wm = (wave >> 1) * 64, wn = (wave & 1) * 64;

  int srow[4], sgj[4];
#pragma unroll
  for (int u = 0; u < 4; u++) {
    int c = u * 256 + tid;
    srow[u] = c >> 3;
    sgj[u] = ((c & 7) ^ (srow[u] & 7)) * 8;
  }

  f32x4 acc[4][4];
  const f32x4 vzero = {0.f, 0.f, 0.f, 0.f};
#pragma unroll
  for (int i = 0; i < 4; i++)
#pragma unroll
    for (int j = 0; j < 4; j++) acc[i][j] = vzero;

  for (int k0 = 0; k0 < DM; k0 += 64) {
    __syncthreads();
#pragma unroll
    for (int u = 0; u < 4; u++) {
      int c = u * 256 + tid;
      async16(A  + (size_t)(m0 + srow[u]) * DM + k0 + sgj[u], (char*)As + c * 16);
      async16(Wt + (size_t)(n0 + srow[u]) * DM + k0 + sgj[u], (char*)Bs + c * 16);
    }
    __syncthreads();

#pragma unroll
    for (int kk = 0; kk < 2; kk++) {
      const int ch = ((kk * 4 + qd) ^ (ln & 7)) * 8;
      bf16x8 af[4], bfr[4];
#pragma unroll
      for (int i = 0; i < 4; i++)
        af[i] = *(const bf16x8*)(As + (wm + i * 16 + ln) * 64 + ch);
#pragma unroll
      for (int j = 0; j < 4; j++)
        bfr[j] = *(const bf16x8*)(Bs + (wn + j * 16 + ln) * 64 + ch);
#pragma unroll
      for (int i = 0; i < 4; i++)
#pragma unroll
        for (int j = 0; j < 4; j++)
          acc[i][j] = __builtin_amdgcn_mfma_f32_16x16x32_bf16(af[i], bfr[j], acc[i][j], 0, 0, 0);
    }
  }

  if (z != 2) {
    unsigned short* C = (z == 0) ? o0 : o1;
    const float sc = (z == 1) ? KSCALE : 1.0f;
#pragma unroll
    for (int j = 0; j < 4; j++) {
      int col = n0 + wn + j * 16 + ln;
      float bj = bias[col];
#pragma unroll
      for (int i = 0; i < 4; i++) {
        int row = m0 + wm + i * 16 + qd * 4;
#pragma unroll
        for (int r = 0; r < 4; r++)
          C[(size_t)(row + r) * DM + col] = f2bf((acc[i][j][r] + bj) * sc);
      }
    }
  } else {
    // direct vT write: vT[(b*H+h)*64+d][SK] with per-64 key permutation
#pragma unroll
    for (int j = 0; j < 4; j++) {
      int col = n0 + wn + j * 16 + ln;
      int h = col >> 6, d = col & 63;
      float bj = bias[col];
#pragma unroll
      for (int i = 0; i < 4; i++) {
        int tok0 = m0 + wm + i * 16 + qd * 4;
        int bb = tok0 >> 11;
        int kcol = ((tok0 & 2047) & ~63) + (i & 1) * 32 + qd * 8 + ((i >> 1) & 1) * 4;
        uint2 u;
        u.x = pk_bf16(acc[i][j][0] + bj, acc[i][j][1] + bj);
        u.y = pk_bf16(acc[i][j][2] + bj, acc[i][j][3] + bj);
        *(uint2*)(vT + ((size_t)(bb * H_ + h) * 64 + d) * SKS + kcol) = u;
      }
    }
  }
}

// ---------------------------------------------------------------------------
// Single GEMM (Wo, ReLU option), BK=64 swizzled, XCD-aware remap
// ---------------------------------------------------------------------------
__global__ __launch_bounds__(256)
void gemm_bf16(const unsigned short* __restrict__ A,
               const unsigned short* __restrict__ Wt,
               const float* __restrict__ bias,
               unsigned short* __restrict__ C,
               int relu)
{
  const int L = blockIdx.x + (blockIdx.y << 3);
  const int g = L & 7, i5 = L >> 3;
  const int nblk = i5 & 7;
  const int mblk = (i5 >> 3) + (g << 3);

  __shared__ short As[128 * 64];
  __shared__ short Bs[128 * 64];
  const int tid = threadIdx.x;
  const int m0 = mblk * 128, n0 = nblk * 128;
  const int wave = tid >> 6, ln = tid & 15, qd = (tid & 63) >> 4;
  const int wm = (wave >> 1) * 64, wn = (wave & 1) * 64;

  int srow[4], sgj[4];
#pragma unroll
  for (int u = 0; u < 4; u++) {
    int c = u * 256 + tid;
    srow[u] = c >> 3;
    sgj[u] = ((c & 7) ^ (srow[u] & 7)) * 8;
  }

  f32x4 acc[4][4];
  const f32x4 vzero = {0.f, 0.f, 0.f, 0.f};
#pragma unroll
  for (int i = 0; i < 4; i++)
#pragma unroll
    for (int j = 0; j < 4; j++) acc[i][j] = vzero;

  for (int k0 = 0; k0 < DM; k0 += 64) {
    __syncthreads();
#pragma unroll
    for (int u = 0; u < 4; u++) {
      int c = u * 256 + tid;
      async16(A  + (size_t)(m0 + srow[u]) * DM + k0 + sgj[u], (char*)As + c * 16);
      async16(Wt + (size_t)(n0 + srow[u]) * DM + k0 + sgj[u], (char*)Bs + c * 16);
    }
    __syncthreads();

#pragma unroll
    for (int kk = 0; kk < 2; kk++) {
      const int ch = ((kk * 4 + qd) ^ (ln & 7)) * 8;
      bf16x8 af[4], bfr[4];
#pragma unroll
      for (int i = 0; i < 4; i++)
        af[i] = *(const bf16x8*)(As + (wm + i * 16 + ln) * 64 + ch);
#pragma unroll
      for (int j = 0; j < 4; j++)
        bfr[j] = *(const bf16x8*)(Bs + (wn + j * 16 + ln) * 64 + ch);
#pragma unroll
      for (int i = 0; i < 4; i++)
#pragma unroll
        for (int j = 0; j < 4; j++)
          acc[i][j] = __builtin_amdgcn_mfma_f32_16x16x32_bf16(af[i], bfr[j], acc[i][j], 0, 0, 0);
    }
  }

#pragma unroll
  for (int j = 0; j < 4; j++) {
    int col = n0 + wn + j * 16 + ln;
    float bj = bias[col];
#pragma unroll
    for (int i = 0; i < 4; i++) {
      int row = m0 + wm + i * 16 + qd * 4;
#pragma unroll
      for (int r = 0; r < 4; r++) {
        float v = acc[i][j][r] + bj;
        if (relu) v = fmaxf(v, 0.f);
        C[(size_t)(row + r) * DM + col] = f2bf(v);
      }
    }
  }
}

// ---------------------------------------------------------------------------
// Flash attention fwd, K-split=2. Block = 256 q x 1024 keys (8 k-tiles of 128).
// grid 1024; launch_bounds(256,2) -> natural VGPR ~116 (NO spill; bounds(256,4)
// in R6 forced accumulator spill to scratch: 2.2 GB traffic). HW still fits
// 4 blocks/CU: VGPR 116 -> 4 waves/SIMD, LDS 33.3KB*4 <= 160KB.
// Writes UNNORMALIZED O-half (bf16) + l (fp32); merge fused into LN1.
// ---------------------------------------------------------------------------
__global__ __launch_bounds__(256, 2)
void attn_fwd(const unsigned short* __restrict__ qp,
              const unsigned short* __restrict__ kp,
              const unsigned short* __restrict__ vT,
              const float* __restrict__ maskb,
              unsigned short* __restrict__ O0,   // [MT][DM] unnormalized, half 0
              unsigned short* __restrict__ O1,   // half 1
              float* __restrict__ lws)           // [2][(b*H+h)*SQS + q]
{
  __shared__ short Ks[128 * 64];    // [key][d],  swizzled 16B chunks
  __shared__ short Vs[64 * 128];    // [d][k'],   swizzled 16B chunks
  __shared__ float bias_s[128];

  const int tid = threadIdx.x;
  // grid = 1024 linear; L%8 = XCD; per XCD: 8 bh x (8 qblk x 2 half)
  const int L = blockIdx.x + (blockIdx.y << 4) + (blockIdx.z << 8);
  const int g = L & 7, i5 = L >> 3;
  const int half = i5 & 1;
  const int qblk = (i5 >> 1) & 7;
  const int bh = (i5 >> 4) + (g << 3);   // [0,64)
  const int h = bh & 15, b = bh >> 4;
  const int q0 = qblk * 256;
  const int koff0 = half * (SKS / 2);
  const int wave = tid >> 6, ln = tid & 15, qd = (tid & 63) >> 4;

  int kRow[4], kOff[4], vRow[4], vOff[4];
#pragma unroll
  for (int u = 0; u < 4; u++) {
    int c = u * 256 + tid;
    kRow[u] = c >> 3;
    kOff[u] = ((c & 7) ^ (kRow[u] & 7)) * 8;
    vRow[u] = c >> 4;
    int j = c & 15;
    vOff[u] = ((j & 8) | ((j ^ vRow[u]) & 7)) * 8;
  }

  const unsigned short* kbase = kp + (size_t)(b * SKS) * DM + (h << 6);
  const unsigned short* vbase = vT + (size_t)((b * H_ + h) * 64) * SKS;

  // Q fragments: 4 q-groups x 2 d-halves (B-operand layout), once per block
  bf16x8 qf[4][2];
#pragma unroll
  for (int gq = 0; gq < 4; gq++) {
    const unsigned short* qrow =
        qp + (size_t)(b * SQS + q0 + wave * 64 + gq * 16 + ln) * DM + (h << 6);
    qf[gq][0] = *(const bf16x8*)(qrow + qd * 8);
    qf[gq][1] = *(const bf16x8*)(qrow + 32 + qd * 8);
  }

  union { bf16x8 v; unsigned int u[4]; } onesf;
  onesf.u[0] = onesf.u[1] = onesf.u[2] = onesf.u[3] = 0x3F803F80u;

  const f32x4 vzero = {0.f, 0.f, 0.f, 0.f};
  f32x4 oA[4][4], lacc[4];
#pragma unroll
  for (int gq = 0; gq < 4; gq++) {
    lacc[gq] = vzero;
#pragma unroll
    for (int t = 0; t < 4; t++) oA[gq][t] = vzero;
  }

  for (int kt = 0; kt < SKS / 2 / 128; kt++) {
    const int k0 = koff0 + kt * 128;
    __syncthreads();
    if (tid < 128) bias_s[tid] = maskb[b * SKS + k0 + tid];
#pragma unroll
    for (int u = 0; u < 4; u++) {
      int c = u * 256 + tid;
      async16(kbase + (size_t)(k0 + kRow[u]) * DM + kOff[u], (char*)Ks + c * 16);
      async16(vbase + (size_t)vRow[u] * SKS + k0 + vOff[u], (char*)Vs + c * 16);
    }
    __syncthreads();

#pragma unroll
    for (int h2 = 0; h2 < 2; h2++) {
      // hoisted K fragments + bias (shared by all 4 q-groups)
      bf16x8 kf[4][2];
      f32x4 btv[4];
#pragma unroll
      for (int t = 0; t < 4; t++) {
        const short* krow = Ks + (h2 * 64 + t * 16 + ln) * 64;
        kf[t][0] = *(const bf16x8*)(krow + ((0 + qd) ^ (ln & 7)) * 8);
        kf[t][1] = *(const bf16x8*)(krow + ((4 + qd) ^ (ln & 7)) * 8);
        btv[t] = *(const f32x4*)(bias_s + h2 * 64 + t * 16 + qd * 4);
      }

      bf16x8 pf[4][2];
#pragma unroll
      for (int gq = 0; gq < 4; gq++) {
        f32x4 sS[4];
#pragma unroll
        for (int t = 0; t < 4; t++) {
          f32x4 a = __builtin_amdgcn_mfma_f32_16x16x32_bf16(kf[t][0], qf[gq][0], btv[t], 0, 0, 0);
          sS[t]   = __builtin_amdgcn_mfma_f32_16x16x32_bf16(kf[t][1], qf[gq][1], a,      0, 0, 0);
        }
        float p[4][4];
#pragma unroll
        for (int t = 0; t < 4; t++) {
          p[t][0] = fexp2(sS[t][0]);
          p[t][1] = fexp2(sS[t][1]);
          p[t][2] = fexp2(sS[t][2]);
          p[t][3] = fexp2(sS[t][3]);
        }
        union { bf16x8 v; unsigned int u[4]; } P0, P1;
        P0.u[0] = pk_trunc(p[0][0], p[0][1]);
        P0.u[1] = pk_trunc(p[0][2], p[0][3]);
        P0.u[2] = pk_trunc(p[2][0], p[2][1]);
        P0.u[3] = pk_trunc(p[2][2], p[2][3]);
        P1.u[0] = pk_trunc(p[1][0], p[1][1]);
        P1.u[1] = pk_trunc(p[1][2], p[1][3]);
        P1.u[2] = pk_trunc(p[3][0], p[3][1]);
        P1.u[3] = pk_trunc(p[3][2], p[3][3]);
        pf[gq][0] = P0.v;
        pf[gq][1] = P1.v;
        lacc[gq] = __builtin_amdgcn_mfma_f32_16x16x32_bf16(pf[gq][0], onesf.v, lacc[gq], 0, 0, 0);
        lacc[gq] = __builtin_amdgcn_mfma_f32_16x16x32_bf16(pf[gq][1], onesf.v, lacc[gq], 0, 0, 0);
      }

      // ---- O += P V, V fragments shared across the 4 q-groups ----
#pragma unroll
      for (int t2 = 0; t2 < 4; t2++) {
        const short* vrow = Vs + (t2 * 16 + ln) * 128;
        bf16x8 vf0 = *(const bf16x8*)(vrow + (h2 * 8 + ((0 + qd) ^ (ln & 7))) * 8);
        bf16x8 vf1 = *(const bf16x8*)(vrow + (h2 * 8 + ((4 + qd) ^ (ln & 7))) * 8);
#pragma unroll
        for (int gq = 0; gq < 4; gq++) {
          oA[gq][t2] = __builtin_amdgcn_mfma_f32_16x16x32_bf16(pf[gq][0], vf0, oA[gq][t2], 0, 0, 0);
          oA[gq][t2] = __builtin_amdgcn_mfma_f32_16x16x32_bf16(pf[gq][1], vf1, oA[gq][t2], 0, 0, 0);
        }
      }
    }
  }

  // ---- epilogue: store UNNORMALIZED O-half + l ----
  unsigned short* obuf = half ? O1 : O0;
  float* lbuf = lws + (size_t)half * (B_ * H_ * SQS);
#pragma unroll
  for (int gq = 0; gq < 4; gq++) {
    int qloc = q0 + wave * 64 + gq * 16 + qd * 4;
    if (ln == 0) {
#pragma unroll
      for (int r = 0; r < 4; r++)
        lbuf[(size_t)(b * H_ + h) * SQS + qloc + r] = lacc[gq][r];
    }
#pragma unroll
    for (int t2 = 0; t2 < 4; t2++)
#pragma unroll
      for (int r = 0; r < 4; r++) {
        size_t idx = (size_t)(b * SQS + qloc + r) * DM + (h << 6) + t2 * 16 + ln;
        obuf[idx] = f2bf(oA[gq][t2][r]);
      }
  }
}

// ---------------------------------------------------------------------------
// LayerNorm(qp + (O0+O1)/(l0+l1)) * g + b -> bf16 (fused K-split merge + LN1)
// ---------------------------------------------------------------------------
__global__ __launch_bounds__(256)
void ln_merge(const unsigned short* __restrict__ Xa, const unsigned short* __restrict__ O0,
              const unsigned short* __restrict__ O1, const float* __restrict__ lws,
              const float* __restrict__ gamma, const float* __restrict__ beta,
              unsigned short* __restrict__ outb)
{
  const int row = blockIdx.x, tid = threadIdx.x;
  const int b = row >> 11, q = row & 2047;
  const int h = tid >> 4;
  const size_t lidx = (size_t)(b * H_ + h) * SQS + q;
  float la = lws[lidx], lb2 = lws[lidx + (size_t)(B_ * H_ * SQS)];
  float lsum = la + lb2;
  float linv = (lsum > 0.f) ? 1.0f / lsum : 0.f;

  const size_t base = (size_t)row * DM + tid * 4;
  uint2 ua = *(const uint2*)(Xa + base);
  uint2 u0 = *(const uint2*)(O0 + base);
  uint2 u1 = *(const uint2*)(O1 + base);
  float v0 = bf2f(ua.x & 0xffffu) + (bf2f(u0.x & 0xffffu) + bf2f(u1.x & 0xffffu)) * linv;
  float v1 = bf2f(ua.x >> 16)     + (bf2f(u0.x >> 16)     + bf2f(u1.x >> 16))     * linv;
  float v2 = bf2f(ua.y & 0xffffu) + (bf2f(u0.y & 0xffffu) + bf2f(u1.y & 0xffffu)) * linv;
  float v3 = bf2f(ua.y >> 16)     + (bf2f(u0.y >> 16)     + bf2f(u1.y >> 16))     * linv;

  float s  = (v0 + v1) + (v2 + v3);
  float s2 = (v0 * v0 + v1 * v1) + (v2 * v2 + v3 * v3);
#pragma unroll
  for (int off = 1; off < 64; off <<= 1) {
    s  += __shfl_xor(s, off);
    s2 += __shfl_xor(s2, off);
  }
  __shared__ float red[8];
  if ((tid & 63) == 0) { red[tid >> 6] = s; red[4 + (tid >> 6)] = s2; }
  __syncthreads();
  float S  = (red[0] + red[1]) + (red[2] + red[3]);
  float S2 = (red[4] + red[5]) + (red[6] + red[7]);
  float mean = S * (1.0f / 1024.0f);
  float var  = S2 * (1.0f / 1024.0f) - mean * mean;
  float rstd = rsqrtf(var + 1e-6f);
  int c = tid * 4;
  float o0 = (v0 - mean) * rstd * gamma[c + 0] + beta[c + 0];
  float o1 = (v1 - mean) * rstd * gamma[c + 1] + beta[c + 1];
  float o2 = (v2 - mean) * rstd * gamma[c + 2] + beta[c + 2];
  float o3 = (v3 - mean) * rstd * gamma[c + 3] + beta[c + 3];
  uint2 o;
  o.x = pk_bf16(o0, o1);
  o.y = pk_bf16(o2, o3);
  *(uint2*)(outb + base) = o;
}

// ---------------------------------------------------------------------------
// LayerNorm(Xa + Xb) * g + b -> fp32 (final LN)
// ---------------------------------------------------------------------------
__global__ __launch_bounds__(256)
void ln_fuse(const unsigned short* __restrict__ Xa, const unsigned short* __restrict__ Xb,
             const float* __restrict__ gamma, const float* __restrict__ beta,
             float* __restrict__ outf)
{
  const int row = blockIdx.x, tid = threadIdx.x;
  const size_t base = (size_t)row * DM + tid * 4;
  uint2 ua = *(const uint2*)(Xa + base);
  uint2 ub = *(const uint2*)(Xb + base);
  float v0 = bf2f(ua.x & 0xffffu) + bf2f(ub.x & 0xffffu);
  float v1 = bf2f(ua.x >> 16)     + bf2f(ub.x >> 16);
  float v2 = bf2f(ua.y & 0xffffu) + bf2f(ub.y & 0xffffu);
  float v3 = bf2f(ua.y >> 16)     + bf2f(ub.y >> 16);
  float s  = (v0 + v1) + (v2 + v3);
  float s2 = (v0 * v0 + v1 * v1) + (v2 * v2 + v3 * v3);
#pragma unroll
  for (int off = 1; off < 64; off <<= 1) {
    s  += __shfl_xor(s, off);
    s2 += __shfl_xor(s2, off);
  }
  __shared__ float red[8];
  if ((tid & 63) == 0) { red[tid >> 6] = s; red[4 + (tid >> 6)] = s2; }
  __syncthreads();
  float S  = (red[0] + red[1]) + (red[2] + red[3]);
  float S2 = (red[4] + red[5]) + (red[6] + red[7]);
  float mean = S * (1.0f / 1024.0f);
  float var  = S2 * (1.0f / 1024.0f) - mean * mean;
  float rstd = rsqrtf(var + 1e-6f);
  int c = tid * 4;
  float o0 = (v0 - mean) * rstd * gamma[c + 0] + beta[c + 0];
  float o1 = (v1 - mean) * rstd * gamma[c + 1] + beta[c + 1];
  float o2 = (v2 - mean) * rstd * gamma[c + 2] + beta[c + 2];
  float o3 = (v3 - mean) * rstd * gamma[c + 3] + beta[c + 3];
  float4 o = {o0, o1, o2, o3};
  *(float4*)(outf + base) = o;
}

// ---------------------------------------------------------------------------
extern "C" void kernel_launch(void* const* d_in, const int* in_sizes, int n_in,
                              void* d_out, int out_size, void* d_ws, size_t ws_size,
                              hipStream_t stream)
{
  (void)in_sizes; (void)n_in; (void)out_size; (void)ws_size;
  const float* q    = (const float*)d_in[0];
  const float* k    = (const float*)d_in[1];
  const float* v    = (const float*)d_in[2];
  const int*   mask = (const int*)  d_in[3];
  const float* Wq   = (const float*)d_in[4];
  const float* bq   = (const float*)d_in[5];
  const float* Wk   = (const float*)d_in[6];
  const float* bk   = (const float*)d_in[7];
  const float* Wv   = (const float*)d_in[8];
  const float* bv   = (const float*)d_in[9];
  const float* Wo   = (const float*)d_in[10];
  const float* bo   = (const float*)d_in[11];
  const float* g1   = (const float*)d_in[12];
  const float* b1   = (const float*)d_in[13];
  const float* g2   = (const float*)d_in[14];
  const float* b2   = (const float*)d_in[15];

  char* ws = (char*)d_ws;
  const size_t SZ16 = (size_t)16 << 20;
  unsigned short* qi   = (unsigned short*)(ws + 0 * SZ16);
  unsigned short* ki   = (unsigned short*)(ws + 1 * SZ16);
  unsigned short* vi   = (unsigned short*)(ws + 2 * SZ16);
  unsigned short* qpb  = (unsigned short*)(ws + 3 * SZ16);
  unsigned short* kpb  = (unsigned short*)(ws + 4 * SZ16);
  unsigned short* vTb  = (unsigned short*)(ws + 6 * SZ16);
  unsigned short* Wqt  = (unsigned short*)(ws + 7 * SZ16 + ((size_t)0 << 20));
  unsigned short* Wkt  = (unsigned short*)(ws + 7 * SZ16 + ((size_t)2 << 20));
  unsigned short* Wvt  = (unsigned short*)(ws + 7 * SZ16 + ((size_t)4 << 20));
  unsigned short* Wot  = (unsigned short*)(ws + 7 * SZ16 + ((size_t)6 << 20));
  float*          mskb = (float*)         (ws + 7 * SZ16 + ((size_t)8 << 20));
  float*          lws  = (float*)         (ws + 7 * SZ16 + ((size_t)9 << 20));  // 2x512KB
  // dead-buffer reuse:
  unsigned short* O0b  = qi;    // free after qkv
  unsigned short* O1b  = vi;    // free after qkv
  unsigned short* xb   = ki;    // free after qkv
  unsigned short* hb   = vTb;   // free after attn

  prep_all     <<<28704,            256, 0, stream>>>(q, k, v, mask, Wq, Wk, Wv, Wo,
                                                      qi, ki, vi, Wqt, Wkt, Wvt, Wot, mskb);

  qkv_gemm     <<<dim3(8, 64, 3),   256, 0, stream>>>(qi, ki, vi, Wqt, Wkt, Wvt,
                                                      bq, bk, bv, qpb, kpb, vTb);

  attn_fwd     <<<dim3(16, 16, 4),  256, 0, stream>>>(qpb, kpb, vTb, mskb, O0b, O1b, lws);

  ln_merge     <<<8192,             256, 0, stream>>>(qpb, O0b, O1b, lws, g1, b1, xb);
  gemm_bf16    <<<dim3(8, 64),      256, 0, stream>>>(xb, Wot, bo, hb, 1);
  ln_fuse      <<<8192,             256, 0, stream>>>(xb, hb, g2, b2, (float*)d_out);
}